// Round 1
// baseline (1455.028 us; speedup 1.0000x reference)
//
#include <hip/hip_runtime.h>

namespace {

constexpr int Hc = 32;   // heads
constexpr int Ec = 64;   // E (and D)
constexpr float EPS = 1e-6f;
constexpr float SCALE = 0.02209708691207961f;  // 2048^{-1/2}
// Row stride 68 floats: rows stay 16B-aligned (272B), and row*68 ≡ 4*row (mod 32)
// so 8 rows with distinct (row mod 8) hit 8 distinct bank quads -> conflict-free b128.
constexpr int LDR = Ec + 4;
constexpr int LDA = Hc + 4;  // 36 floats = 144B, same property for the 32x32 A tile

__device__ __forceinline__ float elu1(float x) {
    // elu(x) + 1 == (x > 0) ? x + 1 : exp(x)
    return x > 0.f ? x + 1.f : __expf(x);
}

__global__ __launch_bounds__(256, 5)
void linattn_kernel(const float* __restrict__ Q,
                    const float* __restrict__ K,
                    const float* __restrict__ V,
                    float* __restrict__ O)
{
    // Reassociated math per (b,l):
    //   A[h][h'] = sum_e qf[h][e] * kf[h'][e]        (32x32, K=64)
    //   y[h]     = 1 / (rowsum(A[h]) + EPS)          (== qf . ksum, exactly)
    //   x[h][d]  = SCALE * y[h] * sum_h' A[h][h'] * V[h'][d]   (32x64, K=32)
    __shared__ float s_qf[Hc][LDR];   // elu(Q)+1
    __shared__ float s_kf[Hc][LDR];   // elu(K)+1
    __shared__ float s_v [Hc][LDR];   // V
    __shared__ float s_A [Hc][LDA];   // qf @ kf^T (unscaled)
    __shared__ float s_y [Hc];        // 1/(rowsum(A)+eps)

    const int tid  = threadIdx.x;
    const int base = blockIdx.x * (Hc * Ec);   // per-(b,l) contiguous 2048-float chunk

    const float4* q4 = reinterpret_cast<const float4*>(Q + base);
    const float4* k4 = reinterpret_cast<const float4*>(K + base);
    const float4* v4 = reinterpret_cast<const float4*>(V + base);

    // ---- Stage Q,K,V into LDS with fused elu+1 (coalesced float4) ----
    #pragma unroll
    for (int i = 0; i < 2; ++i) {
        const int idx = tid + i * 256;       // float4 index 0..511
        const int h   = idx >> 4;            // 16 float4 per row of 64
        const int e4  = (idx & 15) << 2;
        float4 kk = k4[idx];
        float4 qq = q4[idx];
        float4 vv = v4[idx];
        kk.x = elu1(kk.x); kk.y = elu1(kk.y); kk.z = elu1(kk.z); kk.w = elu1(kk.w);
        qq.x = elu1(qq.x); qq.y = elu1(qq.y); qq.z = elu1(qq.z); qq.w = elu1(qq.w);
        *reinterpret_cast<float4*>(&s_kf[h][e4]) = kk;
        *reinterpret_cast<float4*>(&s_qf[h][e4]) = qq;
        *reinterpret_cast<float4*>(&s_v [h][e4]) = vv;
    }
    __syncthreads();

    // ---- Wave 0: A = qf @ kf^T, 4x4 tiles strided by 8 (conflict-free reads) ----
    if (tid < 64) {
        const int i = tid >> 3;   // 0..7 -> rows {i, i+8, i+16, i+24}
        const int j = tid & 7;    // 0..7 -> cols {j, j+8, j+16, j+24}
        float acc[4][4] = {};
        #pragma unroll
        for (int e = 0; e < Ec; e += 4) {
            float4 a[4], b[4];
            #pragma unroll
            for (int r = 0; r < 4; ++r)
                a[r] = *reinterpret_cast<const float4*>(&s_qf[i + 8 * r][e]);
            #pragma unroll
            for (int s = 0; s < 4; ++s)
                b[s] = *reinterpret_cast<const float4*>(&s_kf[j + 8 * s][e]);
            #pragma unroll
            for (int r = 0; r < 4; ++r)
                #pragma unroll
                for (int s = 0; s < 4; ++s) {
                    acc[r][s] = fmaf(a[r].x, b[s].x, acc[r][s]);
                    acc[r][s] = fmaf(a[r].y, b[s].y, acc[r][s]);
                    acc[r][s] = fmaf(a[r].z, b[s].z, acc[r][s]);
                    acc[r][s] = fmaf(a[r].w, b[s].w, acc[r][s]);
                }
        }
        // Write A and fold rowsum -> y via intra-wave shuffle over the j dimension.
        #pragma unroll
        for (int r = 0; r < 4; ++r) {
            float rs = 0.f;
            #pragma unroll
            for (int s = 0; s < 4; ++s) {
                s_A[i + 8 * r][j + 8 * s] = acc[r][s];
                rs += acc[r][s];
            }
            rs += __shfl_xor(rs, 1);
            rs += __shfl_xor(rs, 2);
            rs += __shfl_xor(rs, 4);
            if (j == 0) s_y[i + 8 * r] = 1.f / (rs + EPS);
        }
    }
    __syncthreads();

    // ---- Wave 1: x = A @ V, 4(h, strided 8) x 8(d) tiles over 64 threads ----
    if (tid >= 64 && tid < 128) {
        const int t  = tid - 64;
        const int hg = t >> 3;        // 0..7 -> rows {hg, hg+8, hg+16, hg+24}
        const int dg = t & 7;         // 0..7 -> cols d0..d0+7
        const int d0 = dg << 3;

        float acc[4][8] = {};
        #pragma unroll
        for (int c = 0; c < 8; ++c) {             // h' chunks of 4
            float av[4][4];
            #pragma unroll
            for (int r = 0; r < 4; ++r) {
                const float4 a = *reinterpret_cast<const float4*>(&s_A[hg + 8 * r][c * 4]);
                av[r][0] = a.x; av[r][1] = a.y; av[r][2] = a.z; av[r][3] = a.w;
            }
            #pragma unroll
            for (int m = 0; m < 4; ++m) {
                const int hp = c * 4 + m;
                const float4 b0 = *reinterpret_cast<const float4*>(&s_v[hp][d0]);
                const float4 b1 = *reinterpret_cast<const float4*>(&s_v[hp][d0 + 4]);
                #pragma unroll
                for (int r = 0; r < 4; ++r) {
                    acc[r][0] = fmaf(av[r][m], b0.x, acc[r][0]);
                    acc[r][1] = fmaf(av[r][m], b0.y, acc[r][1]);
                    acc[r][2] = fmaf(av[r][m], b0.z, acc[r][2]);
                    acc[r][3] = fmaf(av[r][m], b0.w, acc[r][3]);
                    acc[r][4] = fmaf(av[r][m], b1.x, acc[r][4]);
                    acc[r][5] = fmaf(av[r][m], b1.y, acc[r][5]);
                    acc[r][6] = fmaf(av[r][m], b1.z, acc[r][6]);
                    acc[r][7] = fmaf(av[r][m], b1.w, acc[r][7]);
                }
            }
        }

        float4* out4 = reinterpret_cast<float4*>(O + base);
        #pragma unroll
        for (int r = 0; r < 4; ++r) {
            const int h  = hg + 8 * r;
            const float yy = s_y[h] * SCALE;
            float4 o0, o1;
            o0.x = acc[r][0] * yy; o0.y = acc[r][1] * yy;
            o0.z = acc[r][2] * yy; o0.w = acc[r][3] * yy;
            o1.x = acc[r][4] * yy; o1.y = acc[r][5] * yy;
            o1.z = acc[r][6] * yy; o1.w = acc[r][7] * yy;
            out4[h * 16 + dg * 2    ] = o0;   // thread writes 32B contiguous
            out4[h * 16 + dg * 2 + 1] = o1;
        }
    }
}

}  // namespace

extern "C" void kernel_launch(void* const* d_in, const int* in_sizes, int n_in,
                              void* d_out, int out_size, void* d_ws, size_t ws_size,
                              hipStream_t stream) {
    const float* Q = reinterpret_cast<const float*>(d_in[0]);
    const float* K = reinterpret_cast<const float*>(d_in[1]);
    const float* V = reinterpret_cast<const float*>(d_in[2]);
    float* O = reinterpret_cast<float*>(d_out);

    const int n_bl = in_sizes[0] / (Hc * Ec);   // B*L = 16384 blocks
    linattn_kernel<<<n_bl, 256, 0, stream>>>(Q, K, V, O);
}

// Round 2
// 385.063 us; speedup vs baseline: 3.7787x; 3.7787x over previous
//
#include <hip/hip_runtime.h>

namespace {

constexpr int Hc = 32;   // heads
constexpr int Ec = 64;   // E (and D)
constexpr float EPS = 1e-6f;
constexpr float SCALE = 0.02209708691207961f;  // 2048^{-1/2}
// Row stride 68 floats: rows 16B-aligned, row*68 ≡ 4*row (mod 32) -> 8 rows with
// distinct (row mod 8) hit 8 distinct bank quads; conflict-free ds_read_b128.
constexpr int LDR = Ec + 4;
constexpr int LDA = Hc + 4;  // 36 floats = 144B rows, same property

__device__ __forceinline__ float elu1(float x) {
    // elu(x) + 1 == (x > 0) ? x + 1 : exp(x)
    return x > 0.f ? x + 1.f : __expf(x);
}

// x_acc += a.{x,y,z,w} (outer) v0..v3
#define XACC(X, A)                                                                 \
    X.x = fmaf(A.x, v0.x, X.x); X.y = fmaf(A.x, v0.y, X.y);                        \
    X.z = fmaf(A.x, v0.z, X.z); X.w = fmaf(A.x, v0.w, X.w);                        \
    X.x = fmaf(A.y, v1.x, X.x); X.y = fmaf(A.y, v1.y, X.y);                        \
    X.z = fmaf(A.y, v1.z, X.z); X.w = fmaf(A.y, v1.w, X.w);                        \
    X.x = fmaf(A.z, v2.x, X.x); X.y = fmaf(A.z, v2.y, X.y);                        \
    X.z = fmaf(A.z, v2.z, X.z); X.w = fmaf(A.z, v2.w, X.w);                        \
    X.x = fmaf(A.w, v3.x, X.x); X.y = fmaf(A.w, v3.y, X.y);                        \
    X.z = fmaf(A.w, v3.z, X.z); X.w = fmaf(A.w, v3.w, X.w);

__global__ __launch_bounds__(128, 4)   // VGPR cap 128: no spill (demand ~70), keeps 7 blocks/CU
void linattn_kernel(const float* __restrict__ Q,
                    const float* __restrict__ K,
                    const float* __restrict__ V,
                    float* __restrict__ O)
{
    // Reassociated math per (b,l):
    //   A[h][h'] = sum_e qf[h][e]*kf[h'][e]   (32x32, K=64)
    //   y[h]     = 1/(rowsum(A[h]) + EPS)     (== qf·ksum exactly)
    //   x[h][d]  = SCALE * y[h] * (A @ V)[h][d]
    __shared__ float s_qf[Hc][LDR];
    __shared__ float s_kf[Hc][LDR];
    __shared__ float s_A [Hc][LDA];
    __shared__ float s_y [Hc];

    const int tid  = threadIdx.x;
    const int base = blockIdx.x * (Hc * Ec);   // per-(b,l) contiguous 2048-float chunk

    const float4* q4 = reinterpret_cast<const float4*>(Q + base);
    const float4* k4 = reinterpret_cast<const float4*>(K + base);
    const float4* v4 = reinterpret_cast<const float4*>(V + base);

    // ---- Stage Q,K into LDS with fused elu+1 (coalesced float4) ----
    #pragma unroll
    for (int i = 0; i < 4; ++i) {
        const int idx = tid + i * 128;       // float4 index 0..511
        const int h   = idx >> 4;            // 16 float4 per row of 64
        const int e4  = (idx & 15) << 2;
        float4 qq = q4[idx];
        float4 kk = k4[idx];
        qq.x = elu1(qq.x); qq.y = elu1(qq.y); qq.z = elu1(qq.z); qq.w = elu1(qq.w);
        kk.x = elu1(kk.x); kk.y = elu1(kk.y); kk.z = elu1(kk.z); kk.w = elu1(kk.w);
        *reinterpret_cast<float4*>(&s_qf[h][e4]) = qq;
        *reinterpret_cast<float4*>(&s_kf[h][e4]) = kk;
    }

    // Prefetch V rows 0..7 (phase-X chunks 0,1) — HBM latency hides under phase A.
    // Lanes 0..15 read one contiguous 256B row; higher lanes broadcast the same rows.
    const int dg = tid & 15;              // d-group: this thread's 4 output columns
    float4 vp0 = v4[0 * 16 + dg], vp1 = v4[1 * 16 + dg];
    float4 vp2 = v4[2 * 16 + dg], vp3 = v4[3 * 16 + dg];
    float4 vp4 = v4[4 * 16 + dg], vp5 = v4[5 * 16 + dg];
    float4 vp6 = v4[6 * 16 + dg], vp7 = v4[7 * 16 + dg];

    __syncthreads();

    // ---- Phase A: A = qf @ kf^T. Both waves, 4x4 tiles, K split by wave. ----
    const int wv = tid >> 6;              // wave 0: e in [0,32), wave 1: e in [32,64)
    const int ln = tid & 63;
    const int ai = ln >> 3;               // rows {ai, ai+8, ai+16, ai+24}
    const int aj = ln & 7;                // cols {aj, aj+8, aj+16, aj+24}
    const int eb = wv << 5;

    float acc[4][4] = {};
    #pragma unroll
    for (int e = 0; e < 32; e += 4) {
        float4 a[4], b[4];
        #pragma unroll
        for (int r = 0; r < 4; ++r)
            a[r] = *reinterpret_cast<const float4*>(&s_qf[ai + 8 * r][eb + e]);
        #pragma unroll
        for (int s = 0; s < 4; ++s)
            b[s] = *reinterpret_cast<const float4*>(&s_kf[aj + 8 * s][eb + e]);
        #pragma unroll
        for (int r = 0; r < 4; ++r)
            #pragma unroll
            for (int s = 0; s < 4; ++s) {
                acc[r][s] = fmaf(a[r].x, b[s].x, acc[r][s]);
                acc[r][s] = fmaf(a[r].y, b[s].y, acc[r][s]);
                acc[r][s] = fmaf(a[r].z, b[s].z, acc[r][s]);
                acc[r][s] = fmaf(a[r].w, b[s].w, acc[r][s]);
            }
    }

    if (wv == 1) {                        // wave 1 parks its partial in s_A
        #pragma unroll
        for (int r = 0; r < 4; ++r)
            #pragma unroll
            for (int s = 0; s < 4; ++s)
                s_A[ai + 8 * r][aj + 8 * s] = acc[r][s];
    }
    __syncthreads();
    if (wv == 0) {                        // wave 0 reduces, writes final A, folds y
        #pragma unroll
        for (int r = 0; r < 4; ++r) {
            float rs = 0.f;
            #pragma unroll
            for (int s = 0; s < 4; ++s) {
                const float fin = acc[r][s] + s_A[ai + 8 * r][aj + 8 * s];
                s_A[ai + 8 * r][aj + 8 * s] = fin;
                rs += fin;
            }
            rs += __shfl_xor(rs, 1);      // reduce over aj (8 lanes)
            rs += __shfl_xor(rs, 2);
            rs += __shfl_xor(rs, 4);
            if (aj == 0) s_y[ai + 8 * r] = 1.f / (rs + EPS);
        }
    }
    __syncthreads();

    // ---- Phase X: x = A @ V. All 128 threads, 4 rows (strided 8) x 4 d-cols. ----
    const int rg = tid >> 4;              // rows {rg, rg+8, rg+16, rg+24}
    float4 x0 = {0, 0, 0, 0}, x1 = {0, 0, 0, 0}, x2 = {0, 0, 0, 0}, x3 = {0, 0, 0, 0};
    #pragma unroll
    for (int c = 0; c < 8; ++c) {         // h' chunks of 4
        const float4 a0 = *reinterpret_cast<const float4*>(&s_A[rg     ][c * 4]);
        const float4 a1 = *reinterpret_cast<const float4*>(&s_A[rg +  8][c * 4]);
        const float4 a2 = *reinterpret_cast<const float4*>(&s_A[rg + 16][c * 4]);
        const float4 a3 = *reinterpret_cast<const float4*>(&s_A[rg + 24][c * 4]);
        float4 v0, v1, v2, v3;
        if (c == 0)      { v0 = vp0; v1 = vp1; v2 = vp2; v3 = vp3; }
        else if (c == 1) { v0 = vp4; v1 = vp5; v2 = vp6; v3 = vp7; }
        else {
            v0 = v4[(c * 4 + 0) * 16 + dg];   // L1/L2-resident: same 256B row per wave
            v1 = v4[(c * 4 + 1) * 16 + dg];
            v2 = v4[(c * 4 + 2) * 16 + dg];
            v3 = v4[(c * 4 + 3) * 16 + dg];
        }
        XACC(x0, a0)
        XACC(x1, a1)
        XACC(x2, a2)
        XACC(x3, a3)
    }

    // ---- Epilogue: scale by y*SCALE, coalesced float4 stores ----
    float4* out4 = reinterpret_cast<float4*>(O + base);
    {
        const float y0 = s_y[rg     ] * SCALE;
        const float y1 = s_y[rg +  8] * SCALE;
        const float y2 = s_y[rg + 16] * SCALE;
        const float y3 = s_y[rg + 24] * SCALE;
        float4 o;
        o.x = x0.x * y0; o.y = x0.y * y0; o.z = x0.z * y0; o.w = x0.w * y0;
        out4[(rg     ) * 16 + dg] = o;
        o.x = x1.x * y1; o.y = x1.y * y1; o.z = x1.z * y1; o.w = x1.w * y1;
        out4[(rg +  8) * 16 + dg] = o;
        o.x = x2.x * y2; o.y = x2.y * y2; o.z = x2.z * y2; o.w = x2.w * y2;
        out4[(rg + 16) * 16 + dg] = o;
        o.x = x3.x * y3; o.y = x3.y * y3; o.z = x3.z * y3; o.w = x3.w * y3;
        out4[(rg + 24) * 16 + dg] = o;
    }
}

}  // namespace

extern "C" void kernel_launch(void* const* d_in, const int* in_sizes, int n_in,
                              void* d_out, int out_size, void* d_ws, size_t ws_size,
                              hipStream_t stream) {
    const float* Q = reinterpret_cast<const float*>(d_in[0]);
    const float* K = reinterpret_cast<const float*>(d_in[1]);
    const float* V = reinterpret_cast<const float*>(d_in[2]);
    float* O = reinterpret_cast<float*>(d_out);

    const int n_bl = in_sizes[0] / (Hc * Ec);   // B*L = 16384 blocks
    linattn_kernel<<<n_bl, 128, 0, stream>>>(Q, K, V, O);
}